// Round 13
// baseline (1832.279 us; speedup 1.0000x reference)
//
#include <hip/hip_runtime.h>
#include <math.h>

typedef unsigned short u16;
typedef unsigned int   u32;
typedef __attribute__((ext_vector_type(8))) short bf16x8;
typedef __attribute__((ext_vector_type(4))) float f32x4;

// ---------------- problem constants ----------------------------------------
// B=8, H=W=256, E=64, HID=128, SUB=16, WS=4, NH=4, dh=16, L=4
// tokens: 2048; residual d [tok][256 px][64 ch] fp32 (ch fastest)
// q/k/v pair-slabs: [tok][256 px][32 ch] bf16 = 32 MB each; only 3 fit.
#define NTOK  2048
#define TOKSZ 16384ull

#define CBAR() __asm__ __volatile__("" ::: "memory")

__device__ __forceinline__ float bf2f(u16 b) { return __uint_as_float(((u32)b) << 16); }
__device__ __forceinline__ u16 f2bf(float f) {
    u32 u = __float_as_uint(f);
    u += 0x7FFFu + ((u >> 16) & 1u);
    return (u16)(u >> 16);
}
__device__ __forceinline__ float gelu_f(float x) {
    return 0.5f * x * (1.0f + erff(x * 0.70710678118654752440f));
}
__device__ __forceinline__ int shift_tok(int n) {
    int w = n >> 4, s = n & 15;
    int b = w >> 4, wy = (w >> 2) & 3, wx = w & 3;
    int ty = s >> 2, tx = s & 3;
    int gy = ((wy << 2) + ty + 2) & 15;
    int gx = ((wx << 2) + tx + 2) & 15;
    int w2 = (b << 4) + ((gy >> 2) << 2) + (gx >> 2);
    int s2 = ((gy & 3) << 2) + (gx & 3);
    return (w2 << 4) + s2;
}
__device__ __forceinline__ int swz(int row, int chunk) {
    return row * 64 + ((chunk ^ (row & 7)) << 3);
}

union U8 { uint4 u; bf16x8 b; };

// ---------------- dtype detection (proven) ---------------------------------
__global__ void detect_kernel(const u16* __restrict__ w1, int* __restrict__ flag) {
    int t = threadIdx.x, bad = 0;
    for (int i = t; i < 640; i += 64) {
        float ax = fabsf(bf2f(w1[i]));
        if (!(ax < 1e3f)) bad = 1;
    }
    unsigned long long m = __ballot(bad);
    if (t == 0) *flag = (m != 0ull) ? 1 : 0;
}

#define NWT 20
struct WArgs { const void* src[NWT]; int off16[NWT + 1]; int f32o[NWT]; };

__global__ __launch_bounds__(256)
void cvt_weights(WArgs a, const int* __restrict__ flag,
                 float* __restrict__ wbufA, u16* __restrict__ wbuf16) {
    int t = blockIdx.x * 256 + threadIdx.x;
    if (t >= a.off16[NWT]) return;
    int s = 0;
    while (a.off16[s + 1] <= t) ++s;
    int idx = t - a.off16[s];
    u16 raw; float v;
    if (*flag) { v = ((const float*)a.src[s])[idx]; raw = f2bf(v); }
    else       { raw = ((const u16*)a.src[s])[idx]; v = bf2f(raw); }
    wbuf16[t] = raw;
    if (a.f32o[s] >= 0) wbufA[a.f32o[s] + idx] = v;
}

// ---------------- embed (proven R10) ---------------------------------------
__global__ __launch_bounds__(256, 3)
void embed_mfma(const void* __restrict__ vin, const int* __restrict__ flag,
                const float* __restrict__ W1, const float* __restrict__ b1,
                const u16* __restrict__ W2bf, const float* __restrict__ b2,
                const int* __restrict__ pdsy, const int* __restrict__ pdsx,
                float* __restrict__ d) {
    extern __shared__ char smem[];
    u16* hsT = (u16*)smem;
    u16* wl  = (u16*)(smem + 32768);
    int n = blockIdx.x, t = threadIdx.x;
    int wv = t >> 6, l = t & 63, m = l & 15, qd = l >> 4;
    int px0 = wv * 64;

    int w = n >> 4, s = n & 15;
    int b = w >> 4, wy = (w >> 2) & 3, wx = w & 3;
    int ty = s >> 2, tx = s & 3;
    int y = ((wy << 2) + ty) * 16 + (t >> 4);
    int x = ((wx << 2) + tx) * 16 + (t & 15);
    int fl = *flag;
    float in0 = ((float)y + 0.5f) * ((float)pdsy[0] * (1.0f / 256.0f));
    float in1 = ((float)x + 0.5f) * ((float)pdsx[0] * (1.0f / 256.0f));
    size_t pix = (size_t)b * 3 * 65536 + (size_t)y * 256 + (size_t)x;
    float in2 = fl ? ((const float*)vin)[pix]          : bf2f(((const u16*)vin)[pix]);
    float in3 = fl ? ((const float*)vin)[pix + 65536]  : bf2f(((const u16*)vin)[pix + 65536]);
    float in4 = fl ? ((const float*)vin)[pix + 131072] : bf2f(((const u16*)vin)[pix + 131072]);

    f32x4 acc[4][4];
    #pragma unroll
    for (int nt = 0; nt < 4; ++nt) {
        float bb = b2[nt * 16 + m];
        #pragma unroll
        for (int mt = 0; mt < 4; ++mt) acc[mt][nt] = {bb, bb, bb, bb};
    }
    for (int half = 0; half < 2; ++half) {
        if (half) __syncthreads();
        for (int h2 = 0; h2 < 64; h2 += 2) {
            int hid = half * 64 + h2;
            float ha = b1[hid] + W1[hid*5]*in0 + W1[hid*5+1]*in1 + W1[hid*5+2]*in2
                     + W1[hid*5+3]*in3 + W1[hid*5+4]*in4;
            float hb2 = b1[hid+1] + W1[hid*5+5]*in0 + W1[hid*5+6]*in1 + W1[hid*5+7]*in2
                     + W1[hid*5+8]*in3 + W1[hid*5+9]*in4;
            u32 pk = (u32)f2bf(gelu_f(ha)) | ((u32)f2bf(gelu_f(hb2)) << 16);
            *(u32*)&hsT[swz(t, h2 >> 3) + (h2 & 7)] = pk;
        }
        #pragma unroll
        for (int r = 0; r < 2; ++r) {
            int u = t + r * 256; int e = u >> 3, c8 = u & 7;
            *(uint4*)&wl[swz(e, c8)] = *(const uint4*)(W2bf + e * 128 + half * 64 + c8 * 8);
        }
        __syncthreads();
        #pragma unroll
        for (int ks = 0; ks < 2; ++ks) {
            U8 af[4], bf[4];
            #pragma unroll
            for (int mt = 0; mt < 4; ++mt)
                af[mt].u = *(const uint4*)&hsT[swz(px0 + mt*16 + m, ks*4 + qd)];
            #pragma unroll
            for (int nt = 0; nt < 4; ++nt)
                bf[nt].u = *(const uint4*)&wl[swz(nt*16 + m, ks*4 + qd)];
            #pragma unroll
            for (int mt = 0; mt < 4; ++mt)
                #pragma unroll
                for (int nt = 0; nt < 4; ++nt)
                    acc[mt][nt] = __builtin_amdgcn_mfma_f32_16x16x32_bf16(
                        af[mt].b, bf[nt].b, acc[mt][nt], 0, 0, 0);
        }
    }
    __syncthreads();
    float* eps = (float*)smem + wv * 2304;
    float* dp = d + (size_t)n * TOKSZ;
    #pragma unroll
    for (int ch2 = 0; ch2 < 2; ++ch2) {
        if (ch2) CBAR();
        #pragma unroll
        for (int mt = ch2*2; mt < ch2*2+2; ++mt)
            #pragma unroll
            for (int nt = 0; nt < 4; ++nt)
                #pragma unroll
                for (int r = 0; r < 4; ++r)
                    eps[((mt&1)*16 + qd*4 + r) * 68 + nt*16 + m] = acc[mt][nt][r];
        CBAR();
        #pragma unroll
        for (int j = 0; j < 8; ++j) {
            int f = l + 64*j; int row = f >> 4, c4 = f & 15;
            float4 v = *(float4*)&eps[row * 68 + c4 * 4];
            *(float4*)&dp[(px0 + ch2*32 + row) * 64 + c4 * 4] = v;
        }
    }
}

// ---------------- fused norm + projection (2 pair GEMMs) — proven R10 ------
__global__ __launch_bounds__(256, 3)
void proj_kernel(const float* __restrict__ d,
                 const u16* __restrict__ Wa, const float* __restrict__ ba,
                 const u16* __restrict__ Wb, const float* __restrict__ bbp,
                 int ha, int hb,
                 u16* __restrict__ oa, u16* __restrict__ obp) {
    extern __shared__ char smem[];
    u16* xs = (u16*)smem;                      // [256][64] swizzled
    u16* wl = (u16*)(smem + 32768);            // [32][64] (aliases sarr)
    float* sarr = (float*)(smem + 32768);
    float* murs = (float*)(smem + 40960);      // 512 B
    u16* ep = (u16*)(smem + 41472);            // 4 * 32*40 u16
    int n = blockIdx.x, t = threadIdx.x;
    const float4* gin = (const float4*)(d + (size_t)n * TOKSZ);
    int cb = (4 * t) & 63, g = t >> 4;
    float4 xv[16];
    float s0=0,s1=0,s2=0,s3=0,q0=0,q1=0,q2=0,q3=0;
    #pragma unroll
    for (int r = 0; r < 16; ++r) {
        float4 v = gin[t + r * 256]; xv[r] = v;
        s0 += v.x; q0 = fmaf(v.x, v.x, q0);
        s1 += v.y; q1 = fmaf(v.y, v.y, q1);
        s2 += v.z; q2 = fmaf(v.z, v.z, q2);
        s3 += v.w; q3 = fmaf(v.w, v.w, q3);
    }
    sarr[(cb+0)*16+g]=s0; sarr[(cb+1)*16+g]=s1; sarr[(cb+2)*16+g]=s2; sarr[(cb+3)*16+g]=s3;
    float* qarr = sarr + 1024;
    qarr[(cb+0)*16+g]=q0; qarr[(cb+1)*16+g]=q1; qarr[(cb+2)*16+g]=q2; qarr[(cb+3)*16+g]=q3;
    __syncthreads();
    if (t < 64) {
        float ss = 0.f, qq = 0.f;
        #pragma unroll
        for (int gg = 0; gg < 16; ++gg) { ss += sarr[t*16+gg]; qq += qarr[t*16+gg]; }
        float mu = ss * (1.0f/256.0f);
        float var = qq * (1.0f/256.0f) - mu * mu;
        murs[t] = mu; murs[64 + t] = rsqrtf(var + 1e-5f);
    }
    __syncthreads();
    {
        float m0 = murs[cb], m1 = murs[cb+1], m2 = murs[cb+2], m3 = murs[cb+3];
        float r0 = murs[64+cb], r1 = murs[64+cb+1], r2 = murs[64+cb+2], r3 = murs[64+cb+3];
        int c4 = t & 15;
        #pragma unroll
        for (int r = 0; r < 16; ++r) {
            float4 v = xv[r];
            int px = (t >> 4) + r * 16;
            uint2 o;
            o.x = (u32)f2bf((v.x-m0)*r0) | ((u32)f2bf((v.y-m1)*r1) << 16);
            o.y = (u32)f2bf((v.z-m2)*r2) | ((u32)f2bf((v.w-m3)*r3) << 16);
            *(uint2*)&xs[swz(px, c4 >> 1) + (c4 & 1) * 4] = o;
        }
    }
    int wv = t >> 6, l = t & 63, m = l & 15, qd = l >> 4;
    int px0 = wv * 64;
    const u16* Ws[2] = {Wa, Wb};
    const float* bs[2] = {ba, bbp};
    u16* outs[2] = {oa, obp};
    int hs[2] = {ha, hb};
    for (int ti = 0; ti < 2; ++ti) {
        if (ti) __syncthreads();
        {
            int e = t >> 3, c8 = t & 7;
            *(uint4*)&wl[swz(e, c8)] =
                *(const uint4*)(Ws[ti] + (size_t)(hs[ti] * 16 + e) * 64 + c8 * 8);
        }
        __syncthreads();
        f32x4 acc[4][2];
        #pragma unroll
        for (int nt = 0; nt < 2; ++nt) {
            float bb = bs[ti][hs[ti] * 16 + nt * 16 + m];
            #pragma unroll
            for (int mt = 0; mt < 4; ++mt) acc[mt][nt] = {bb, bb, bb, bb};
        }
        #pragma unroll
        for (int ks = 0; ks < 2; ++ks) {
            U8 af[4], bf[2];
            #pragma unroll
            for (int mt = 0; mt < 4; ++mt)
                af[mt].u = *(const uint4*)&xs[swz(px0 + mt*16 + m, ks*4 + qd)];
            #pragma unroll
            for (int nt = 0; nt < 2; ++nt)
                bf[nt].u = *(const uint4*)&wl[swz(nt*16 + m, ks*4 + qd)];
            #pragma unroll
            for (int mt = 0; mt < 4; ++mt)
                #pragma unroll
                for (int nt = 0; nt < 2; ++nt)
                    acc[mt][nt] = __builtin_amdgcn_mfma_f32_16x16x32_bf16(
                        af[mt].b, bf[nt].b, acc[mt][nt], 0, 0, 0);
        }
        u16* epw = ep + wv * 1280;
        u16* dst0 = outs[ti] + (size_t)n * 8192;
        #pragma unroll
        for (int ch2 = 0; ch2 < 2; ++ch2) {
            if (ch2) CBAR();
            #pragma unroll
            for (int mt = ch2*2; mt < ch2*2+2; ++mt)
                #pragma unroll
                for (int nt = 0; nt < 2; ++nt)
                    #pragma unroll
                    for (int r = 0; r < 4; ++r)
                        epw[((mt&1)*16 + qd*4 + r) * 40 + nt*16 + m] = f2bf(acc[mt][nt][r]);
            CBAR();
            #pragma unroll
            for (int u = l; u < 128; u += 64) {
                int row = u >> 2, c8 = u & 3;
                *(uint4*)(dst0 + (size_t)(px0 + ch2*32 + row) * 32 + c8*8)
                    = *(uint4*)&epw[row * 40 + c8*8];
            }
        }
    }
}

// ---------------- scores via MFMA + softmax (proven R10) -------------------
__global__ __launch_bounds__(256, 4)
void scores_mfma(const u16* __restrict__ q, const u16* __restrict__ k,
                 int shifted, int hbase, float* __restrict__ A) {
    int w = blockIdx.x, hy = blockIdx.y, t = threadIdx.x;
    int wv = t >> 6, l = t & 63, m = l & 15, qd = l >> 4;
    int n0 = w * 16 + m;
    int ni = shifted ? shift_tok(n0) : n0;
    size_t base = (size_t)ni * 8192 + hy * 16 + (qd & 1) * 8;
    const u16* qrow = q + base;
    const u16* krow = k + base;
    int pxb = wv * 64 + (qd >> 1);
    f32x4 acc = {0.f, 0.f, 0.f, 0.f};
    for (int s = 0; s < 32; ++s) {
        U8 qa, kv;
        qa.u = *(const uint4*)(qrow + (size_t)(pxb + s*2) * 32);
        kv.u = *(const uint4*)(krow + (size_t)(pxb + s*2) * 32);
        acc = __builtin_amdgcn_mfma_f32_16x16x32_bf16(qa.b, kv.b, acc, 0, 0, 0);
    }
    __shared__ float pc[4][256];
    #pragma unroll
    for (int r = 0; r < 4; ++r) pc[wv][l * 4 + r] = acc[r];
    __syncthreads();
    if (wv == 0) {
        float* arow = A + ((size_t)(w * 4 + hbase + hy) * 16) * 16;
        #pragma unroll
        for (int r = 0; r < 4; ++r) {
            float sc = (pc[0][l*4+r] + pc[1][l*4+r] + pc[2][l*4+r] + pc[3][l*4+r])
                     * (1.0f / 1024.0f);
            float mx = sc;
            #pragma unroll
            for (int off = 1; off < 16; off <<= 1) mx = fmaxf(mx, __shfl_xor(mx, off, 16));
            float e = expf(sc - mx);
            float ssum = e;
            #pragma unroll
            for (int off = 1; off < 16; off <<= 1) ssum += __shfl_xor(ssum, off, 16);
            arow[(qd * 4 + r) * 16 + m] = e / ssum;
        }
    }
}

// ---------------- fused A@v + Wo + norm + MLP + residual -------------------
// Residual prefetched at kernel top: its HBM latency hides behind A@v + Wo.
__global__ __launch_bounds__(256, 3)
void wo_av_mlp(const u16* __restrict__ v1, const u16* __restrict__ v2,
               const float* __restrict__ A,
               const u16* __restrict__ Wo, const float* __restrict__ bo,
               const u16* __restrict__ W1, const float* __restrict__ b1,
               const u16* __restrict__ W2, const float* __restrict__ b2,
               int shifted, float* __restrict__ dres) {
    extern __shared__ char smem[];
    u16* xs = (u16*)smem;               // 32 KB: o-tile, then xhat/h
    u16* wl = (u16*)(smem + 32768);     // 8 KB (aliases sarr)
    float* sarr = (float*)(smem + 32768);
    float* murs = (float*)(smem + 40960);
    float* As  = (float*)(smem + 41472);
    int*  nis  = (int*)(smem + 41728);
    int bid = blockIdx.x;
    int qg = bid >> 7, r7 = bid & 127;
    int n = ((qg << 3) + (r7 & 7)) * 16 + (r7 >> 3);
    int t = threadIdx.x;
    int wv = t >> 6, l = t & 63, m = l & 15, qd = l >> 4;
    int px0 = wv * 64;
    int w = n >> 4, i = n & 15;
    int no = shifted ? shift_tok(n) : n;
    int rbase = l >> 4, c4 = l & 15;

    // ---- prefetch residual (consumed only after Wo GEMM; latency hidden) --
    const float4* gin = (const float4*)(dres + (size_t)no * TOKSZ);
    float4 y[2][8];
    #pragma unroll
    for (int ch2 = 0; ch2 < 2; ++ch2)
        #pragma unroll
        for (int j = 0; j < 8; ++j)
            y[ch2][j] = gin[(px0 + ch2*32 + rbase + 4*j) * 16 + c4];

    if (t < 16) { int nn = w * 16 + t; nis[t] = shifted ? shift_tok(nn) : nn; }
    if (t >= 64 && t < 128) {
        int u = t - 64;
        As[u] = A[(size_t)(w * 4 + (u >> 4)) * 256 + i * 16 + (u & 15)];
    }
    #pragma unroll
    for (int r = 0; r < 2; ++r) {
        int u = t + r * 256; int e = u >> 3, c8 = u & 7;
        *(uint4*)&wl[swz(e, c8)] = *(const uint4*)(Wo + e * 64 + c8 * 8);
    }
    __syncthreads();
    // o-tile = A @ v -> xs (bf16)
    #pragma unroll
    for (int r = 0; r < 8; ++r) {
        int idx = r * 256 + t;
        int px = idx >> 3, c8 = idx & 7, h = c8 >> 1;
        float a0=0,a1=0,a2=0,a3=0,a4=0,a5=0,a6=0,a7=0;
        #pragma unroll
        for (int j = 0; j < 16; ++j) {
            const u16* src = (c8 < 4)
                ? (v1 + (size_t)nis[j] * 8192 + px * 32 + c8 * 8)
                : (v2 + (size_t)nis[j] * 8192 + px * 32 + (c8 - 4) * 8);
            uint4 pv = *(const uint4*)src;
            float aw = As[h * 16 + j];
            a0 = fmaf(aw, __uint_as_float(pv.x << 16), a0);
            a1 = fmaf(aw, __uint_as_float(pv.x & 0xFFFF0000u), a1);
            a2 = fmaf(aw, __uint_as_float(pv.y << 16), a2);
            a3 = fmaf(aw, __uint_as_float(pv.y & 0xFFFF0000u), a3);
            a4 = fmaf(aw, __uint_as_float(pv.z << 16), a4);
            a5 = fmaf(aw, __uint_as_float(pv.z & 0xFFFF0000u), a5);
            a6 = fmaf(aw, __uint_as_float(pv.w << 16), a6);
            a7 = fmaf(aw, __uint_as_float(pv.w & 0xFFFF0000u), a7);
        }
        uint4 o;
        o.x = (u32)f2bf(a0) | ((u32)f2bf(a1) << 16);
        o.y = (u32)f2bf(a2) | ((u32)f2bf(a3) << 16);
        o.z = (u32)f2bf(a4) | ((u32)f2bf(a5) << 16);
        o.w = (u32)f2bf(a6) | ((u32)f2bf(a7) << 16);
        *(uint4*)&xs[swz(px, c8)] = o;
    }
    __syncthreads();
    // Wo GEMM
    f32x4 acc[4][4];
    #pragma unroll
    for (int nt = 0; nt < 4; ++nt) {
        float bb = bo[nt * 16 + m];
        #pragma unroll
        for (int mt = 0; mt < 4; ++mt) acc[mt][nt] = {bb, bb, bb, bb};
    }
    #pragma unroll
    for (int ks = 0; ks < 2; ++ks) {
        U8 af[4], bf[4];
        #pragma unroll
        for (int mt = 0; mt < 4; ++mt)
            af[mt].u = *(const uint4*)&xs[swz(px0 + mt*16 + m, ks*4 + qd)];
        #pragma unroll
        for (int nt = 0; nt < 4; ++nt)
            bf[nt].u = *(const uint4*)&wl[swz(nt*16 + m, ks*4 + qd)];
        #pragma unroll
        for (int mt = 0; mt < 4; ++mt)
            #pragma unroll
            for (int nt = 0; nt < 4; ++nt)
                acc[mt][nt] = __builtin_amdgcn_mfma_f32_16x16x32_bf16(
                    af[mt].b, bf[nt].b, acc[mt][nt], 0, 0, 0);
    }
    __syncthreads();
    // transpose delta; y += delta; stats on the fly
    float* eps = (float*)smem + wv * 2304;
    float s0=0,s1=0,s2=0,s3=0,q0=0,q1=0,q2=0,q3=0;
    #pragma unroll
    for (int ch2 = 0; ch2 < 2; ++ch2) {
        if (ch2) CBAR();
        #pragma unroll
        for (int mt = ch2*2; mt < ch2*2+2; ++mt)
            #pragma unroll
            for (int nt = 0; nt < 4; ++nt)
                #pragma unroll
                for (int r = 0; r < 4; ++r)
                    eps[((mt&1)*16 + qd*4 + r) * 68 + nt*16 + m] = acc[mt][nt][r];
        CBAR();
        #pragma unroll
        for (int j = 0; j < 8; ++j) {
            int row = rbase + 4*j;
            float4 dv = *(float4*)&eps[row * 68 + c4 * 4];
            float4 rv = y[ch2][j];
            rv.x += dv.x; rv.y += dv.y; rv.z += dv.z; rv.w += dv.w;
            y[ch2][j] = rv;
            s0 += rv.x; q0 = fmaf(rv.x, rv.x, q0);
            s1 += rv.y; q1 = fmaf(rv.y, rv.y, q1);
            s2 += rv.z; q2 = fmaf(rv.z, rv.z, q2);
            s3 += rv.w; q3 = fmaf(rv.w, rv.w, q3);
        }
    }
    __syncthreads();                 // eps (overlaps sarr region) fully read
    int cb = 4 * c4, g = t >> 4;
    sarr[(cb+0)*16+g]=s0; sarr[(cb+1)*16+g]=s1; sarr[(cb+2)*16+g]=s2; sarr[(cb+3)*16+g]=s3;
    float* qarr = sarr + 1024;
    qarr[(cb+0)*16+g]=q0; qarr[(cb+1)*16+g]=q1; qarr[(cb+2)*16+g]=q2; qarr[(cb+3)*16+g]=q3;
    __syncthreads();
    if (t < 64) {
        float ss = 0.f, qq = 0.f;
        #pragma unroll
        for (int gg = 0; gg < 16; ++gg) { ss += sarr[t*16+gg]; qq += qarr[t*16+gg]; }
        float mu = ss * (1.0f/256.0f);
        float var = qq * (1.0f/256.0f) - mu * mu;
        murs[t] = mu; murs[64 + t] = rsqrtf(var + 1e-5f);
    }
    __syncthreads();
    {
        float m0 = murs[cb], m1 = murs[cb+1], m2 = murs[cb+2], m3 = murs[cb+3];
        float r0 = murs[64+cb], r1 = murs[64+cb+1], r2 = murs[64+cb+2], r3 = murs[64+cb+3];
        #pragma unroll
        for (int ch2 = 0; ch2 < 2; ++ch2)
            #pragma unroll
            for (int j = 0; j < 8; ++j) {
                float4 v = y[ch2][j];
                int row = px0 + ch2*32 + rbase + 4*j;
                uint2 o;
                o.x = (u32)f2bf((v.x-m0)*r0) | ((u32)f2bf((v.y-m1)*r1) << 16);
                o.y = (u32)f2bf((v.z-m2)*r2) | ((u32)f2bf((v.w-m3)*r3) << 16);
                *(uint2*)&xs[swz(row, c4 >> 1) + (c4 & 1) * 4] = o;
            }
    }
    #pragma unroll
    for (int r = 0; r < 2; ++r) {
        int u = t + r * 256; int e = u >> 3, c8 = u & 7;
        *(uint4*)&wl[swz(e, c8)] = *(const uint4*)(W1 + e * 64 + c8 * 8);
    }
    __syncthreads();
    #pragma unroll
    for (int nt = 0; nt < 4; ++nt) {
        float bb = b1[nt * 16 + m];
        #pragma unroll
        for (int mt = 0; mt < 4; ++mt) acc[mt][nt] = {bb, bb, bb, bb};
    }
    #pragma unroll
    for (int ks = 0; ks < 2; ++ks) {
        U8 af[4], bf[4];
        #pragma unroll
        for (int mt = 0; mt < 4; ++mt)
            af[mt].u = *(const uint4*)&xs[swz(px0 + mt*16 + m, ks*4 + qd)];
        #pragma unroll
        for (int nt = 0; nt < 4; ++nt)
            bf[nt].u = *(const uint4*)&wl[swz(nt*16 + m, ks*4 + qd)];
        #pragma unroll
        for (int mt = 0; mt < 4; ++mt)
            #pragma unroll
            for (int nt = 0; nt < 4; ++nt)
                acc[mt][nt] = __builtin_amdgcn_mfma_f32_16x16x32_bf16(
                    af[mt].b, bf[nt].b, acc[mt][nt], 0, 0, 0);
    }
    __syncthreads();
    #pragma unroll
    for (int nt = 0; nt < 4; ++nt) {
        int ch = nt * 16 + m;
        #pragma unroll
        for (int mt = 0; mt < 4; ++mt)
            #pragma unroll
            for (int r = 0; r < 4; ++r) {
                int R = px0 + mt*16 + qd*4 + r;
                xs[swz(R, ch >> 3) + (ch & 7)] = f2bf(gelu_f(acc[mt][nt][r]));
            }
    }
    #pragma unroll
    for (int r = 0; r < 2; ++r) {
        int u = t + r * 256; int e = u >> 3, c8 = u & 7;
        *(uint4*)&wl[swz(e, c8)] = *(const uint4*)(W2 + e * 64 + c8 * 8);
    }
    __syncthreads();
    #pragma unroll
    for (int nt = 0; nt < 4; ++nt) {
        float bb = b2[nt * 16 + m];
        #pragma unroll
        for (int mt = 0; mt < 4; ++mt) acc[mt][nt] = {bb, bb, bb, bb};
    }
    #pragma unroll
    for (int ks = 0; ks < 2; ++ks) {
        U8 af[4], bf[4];
        #pragma unroll
        for (int mt = 0; mt < 4; ++mt)
            af[mt].u = *(const uint4*)&xs[swz(px0 + mt*16 + m, ks*4 + qd)];
        #pragma unroll
        for (int nt = 0; nt < 4; ++nt)
            bf[nt].u = *(const uint4*)&wl[swz(nt*16 + m, ks*4 + qd)];
        #pragma unroll
        for (int mt = 0; mt < 4; ++mt)
            #pragma unroll
            for (int nt = 0; nt < 4; ++nt)
                acc[mt][nt] = __builtin_amdgcn_mfma_f32_16x16x32_bf16(
                    af[mt].b, bf[nt].b, acc[mt][nt], 0, 0, 0);
    }
    __syncthreads();
    float* dp = dres + (size_t)no * TOKSZ;
    #pragma unroll
    for (int ch2 = 0; ch2 < 2; ++ch2) {
        if (ch2) CBAR();
        #pragma unroll
        for (int mt = ch2*2; mt < ch2*2+2; ++mt)
            #pragma unroll
            for (int nt = 0; nt < 4; ++nt)
                #pragma unroll
                for (int r = 0; r < 4; ++r)
                    eps[((mt&1)*16 + qd*4 + r) * 68 + nt*16 + m] = acc[mt][nt][r];
        CBAR();
        #pragma unroll
        for (int j = 0; j < 8; ++j) {
            int row = rbase + 4*j;
            float4 dv = *(float4*)&eps[row * 68 + c4 * 4];
            float4 bsv = y[ch2][j];
            bsv.x += dv.x; bsv.y += dv.y; bsv.z += dv.z; bsv.w += dv.w;
            *(float4*)&dp[(px0 + ch2*32 + row) * 64 + c4 * 4] = bsv;
        }
    }
}

// ---------------- output MLP via MFMA (proven R10) -------------------------
__global__ __launch_bounds__(256, 3)
void out_mfma(const float* __restrict__ d,
              const u16* __restrict__ W1, const float* __restrict__ b1,
              const float* __restrict__ W2, const float* __restrict__ b2,
              void* __restrict__ out, const int* __restrict__ flag) {
    extern __shared__ char smem[];
    u16* xs = (u16*)smem;
    u16* wl = (u16*)(smem + 32768);
    int n = blockIdx.x, t = threadIdx.x;
    int wv = t >> 6, l = t & 63, m = l & 15, qd = l >> 4;
    int px0 = wv * 64;
    const float4* gin = (const float4*)(d + (size_t)n * TOKSZ);
    #pragma unroll
    for (int r = 0; r < 16; ++r) {
        float4 xv = gin[t + r * 256];
        int fi = t + r * 256;
        int px = fi >> 4, c4 = fi & 15;
        uint2 o;
        o.x = (u32)f2bf(xv.x) | ((u32)f2bf(xv.y) << 16);
        o.y = (u32)f2bf(xv.z) | ((u32)f2bf(xv.w) << 16);
        *(uint2*)&xs[swz(px, c4 >> 1) + (c4 & 1) * 4] = o;
    }
    float val[4][4];
    #pragma unroll
    for (int mt = 0; mt < 4; ++mt)
        #pragma unroll
        for (int r = 0; r < 4; ++r) val[mt][r] = 0.f;
    for (int nh = 0; nh < 2; ++nh) {
        if (nh) __syncthreads();
        #pragma unroll
        for (int r = 0; r < 2; ++r) {
            int u = t + r * 256;
            int e = u >> 3, c8 = u & 7;
            *(uint4*)&wl[swz(e, c8)] = *(const uint4*)(W1 + (size_t)nh * 4096 + e * 64 + c8 * 8);
        }
        __syncthreads();
        f32x4 acc[4][4];
        #pragma unroll
        for (int nt = 0; nt < 4; ++nt) {
            float bb = b1[nh * 64 + nt * 16 + m];
            #pragma unroll
            for (int mt = 0; mt < 4; ++mt) acc[mt][nt] = {bb, bb, bb, bb};
        }
        #pragma unroll
        for (int ks = 0; ks < 2; ++ks) {
            U8 af[4], bf[4];
            #pragma unroll
            for (int mt = 0; mt < 4; ++mt)
                af[mt].u = *(const uint4*)&xs[swz(px0 + mt*16 + m, ks*4 + qd)];
            #pragma unroll
            for (int nt = 0; nt < 4; ++nt)
                bf[nt].u = *(const uint4*)&wl[swz(nt*16 + m, ks*4 + qd)];
            #pragma unroll
            for (int mt = 0; mt < 4; ++mt)
                #pragma unroll
                for (int nt = 0; nt < 4; ++nt)
                    acc[mt][nt] = __builtin_amdgcn_mfma_f32_16x16x32_bf16(
                        af[mt].b, bf[nt].b, acc[mt][nt], 0, 0, 0);
        }
        float w2v[4];
        #pragma unroll
        for (int nt = 0; nt < 4; ++nt) w2v[nt] = W2[nh * 64 + nt * 16 + m];
        #pragma unroll
        for (int mt = 0; mt < 4; ++mt)
            #pragma unroll
            for (int r = 0; r < 4; ++r) {
                float p = 0.f;
                #pragma unroll
                for (int nt = 0; nt < 4; ++nt)
                    p = fmaf(gelu_f(acc[mt][nt][r]), w2v[nt], p);
                val[mt][r] += p;
            }
    }
    __syncthreads();
    float* red = (float*)smem;
    #pragma unroll
    for (int mt = 0; mt < 4; ++mt)
        #pragma unroll
        for (int r = 0; r < 4; ++r)
            red[(px0 + mt*16 + qd*4 + r) * 17 + m] = val[mt][r];
    __syncthreads();
    float a = b2[0];
    #pragma unroll
    for (int j = 0; j < 16; ++j) a += red[t * 17 + j];
    int w = n >> 4, s = n & 15;
    int b = w >> 4, wy = (w >> 2) & 3, wx = w & 3;
    int ty = s >> 2, tx = s & 3;
    int y = ((wy << 2) + ty) * 16 + (t >> 4);
    int x = ((wx << 2) + tx) * 16 + (t & 15);
    size_t oi = (size_t)b * 65536 + (size_t)y * 256 + (size_t)x;
    if (*flag) ((float*)out)[oi] = a;
    else       ((u16*)out)[oi] = f2bf(a);
}

// ---------------- host launch ----------------------------------------------
extern "C" void kernel_launch(void* const* d_in, const int* in_sizes, int n_in,
                              void* d_out, int out_size, void* d_ws, size_t ws_size,
                              hipStream_t stream) {
    (void)n_in; (void)out_size; (void)ws_size;
    const int* pdsy = (const int*)d_in[21];
    const int* pdsx = (const int*)d_in[22];

    // proven 235.65 MB layout
    char* wsb = (char*)d_ws;
    float* bufd = (float*)wsb;
    u16* qb = (u16*)(wsb + 134217728ull);
    u16* kb = (u16*)(wsb + 167772160ull);
    u16* vb = (u16*)(wsb + 201326592ull);
    float* A     = (float*)(wsb + 234881024ull);
    float* wbufA = (float*)(wsb + 235405312ull);
    u16* wbuf16  = (u16*)(wsb + 235416064ull);
    int* flag    = (int*)(wsb + 235650816ull);

    const int f32set[12] = {1, 2, 4, 6, 8, 10, 12, 14, 16, 18, 19, 20};
    WArgs wa;
    int off16[NWT + 1]; off16[0] = 0;
    int c32[NWT + 1];
    int fo = 0;
    for (int i = 0; i < NWT; ++i) {
        int di = i + 1;
        wa.src[i] = d_in[di];
        off16[i + 1] = off16[i] + in_sizes[di];
        wa.off16[i] = off16[i];
        int isf = 0;
        for (int j = 0; j < 12; ++j) if (f32set[j] == di) isf = 1;
        wa.f32o[i] = isf ? fo : -1;
        c32[di] = isf ? fo : -1;
        if (isf) fo += in_sizes[di];
    }
    wa.off16[NWT] = off16[NWT];

    detect_kernel<<<1, 64, 0, stream>>>((const u16*)d_in[1], flag);
    cvt_weights<<<(off16[NWT] + 255) / 256, 256, 0, stream>>>(wa, flag, wbufA, wbuf16);

    const float* f_inpW1 = wbufA + c32[1];
    const float* f_inpb1 = wbufA + c32[2];
    const float* f_inpb2 = wbufA + c32[4];
    const float* f_bq  = wbufA + c32[6];
    const float* f_bk  = wbufA + c32[8];
    const float* f_bv  = wbufA + c32[10];
    const float* f_bo  = wbufA + c32[12];
    const float* f_mb1 = wbufA + c32[14];
    const float* f_mb2 = wbufA + c32[16];
    const float* f_ob1 = wbufA + c32[18];
    const float* f_oW2 = wbufA + c32[19];
    const float* f_ob2 = wbufA + c32[20];
    const u16* h_inpW2 = wbuf16 + off16[2];
    const u16* h_Wq  = wbuf16 + off16[4];
    const u16* h_Wk  = wbuf16 + off16[6];
    const u16* h_Wv  = wbuf16 + off16[8];
    const u16* h_Wo  = wbuf16 + off16[10];
    const u16* h_mW1 = wbuf16 + off16[12];
    const u16* h_mW2 = wbuf16 + off16[14];
    const u16* h_oW1 = wbuf16 + off16[16];

    embed_mfma<<<NTOK, 256, 40960, stream>>>(d_in[0], flag, f_inpW1, f_inpb1,
                                             h_inpW2, f_inpb2, pdsy, pdsx, bufd);

    for (int l = 0; l < 4; ++l) {
        int sh = l & 1;
        const u16* Wql = h_Wq + l * 4096;  const float* bql = f_bq + l * 64;
        const u16* Wkl = h_Wk + l * 4096;  const float* bkl = f_bk + l * 64;
        const u16* Wvl = h_Wv + l * 4096;  const float* bvl = f_bv + l * 64;

        proj_kernel<<<NTOK, 256, 51712, stream>>>(bufd, Wql, bql, Wkl, bkl, 0, 0, qb, kb);
        scores_mfma<<<dim3(128, 2), 256, 0, stream>>>(qb, kb, sh, 0, A);
        proj_kernel<<<NTOK, 256, 51712, stream>>>(bufd, Wql, bql, Wkl, bkl, 2, 2, qb, kb);
        scores_mfma<<<dim3(128, 2), 256, 0, stream>>>(qb, kb, sh, 2, A);
        proj_kernel<<<NTOK, 256, 51712, stream>>>(bufd, Wvl, bvl, Wvl, bvl, 0, 2, vb, kb);
        wo_av_mlp<<<NTOK, 256, 41792, stream>>>(vb, kb, A,
            h_Wo + l * 4096, f_bo + l * 64,
            h_mW1 + l * 4096, f_mb1 + l * 64,
            h_mW2 + l * 4096, f_mb2 + l * 64, sh, bufd);
    }

    out_mfma<<<NTOK, 256, 40960, stream>>>(bufd, h_oW1, f_ob1, f_oW2, f_ob2,
                                           d_out, flag);
}

// Round 14
// 1503.367 us; speedup vs baseline: 1.2188x; 1.2188x over previous
//
#include <hip/hip_runtime.h>
#include <math.h>

typedef unsigned short u16;
typedef unsigned int   u32;
typedef __attribute__((ext_vector_type(8))) short bf16x8;
typedef __attribute__((ext_vector_type(4))) float f32x4;

// ---------------- problem constants ----------------------------------------
// B=8, H=W=256, E=64, HID=128, SUB=16, WS=4, NH=4, dh=16, L=4
// tokens: 2048; residual d [tok][256 px][64 ch] fp32 (ch fastest)
// q/k/v slabs: [tok][256 px][32 ch] bf16 (one head-pair)
#define NTOK  2048
#define TOKSZ 16384ull

#define CBAR() __asm__ __volatile__("" ::: "memory")

__device__ __forceinline__ float bf2f(u16 b) { return __uint_as_float(((u32)b) << 16); }
__device__ __forceinline__ u16 f2bf(float f) {
    u32 u = __float_as_uint(f);
    u += 0x7FFFu + ((u >> 16) & 1u);
    return (u16)(u >> 16);
}
__device__ __forceinline__ float gelu_f(float x) {
    return 0.5f * x * (1.0f + erff(x * 0.70710678118654752440f));
}
__device__ __forceinline__ int shift_tok(int n) {
    int w = n >> 4, s = n & 15;
    int b = w >> 4, wy = (w >> 2) & 3, wx = w & 3;
    int ty = s >> 2, tx = s & 3;
    int gy = ((wy << 2) + ty + 2) & 15;
    int gx = ((wx << 2) + tx + 2) & 15;
    int w2 = (b << 4) + ((gy >> 2) << 2) + (gx >> 2);
    int s2 = ((gy & 3) << 2) + (gx & 3);
    return (w2 << 4) + s2;
}
// XOR-swizzled u16 tile index: row stride 64, chunk = 8 u16
__device__ __forceinline__ int swz(int row, int chunk) {
    return row * 64 + ((chunk ^ (row & 7)) << 3);
}

union U8 { uint4 u; bf16x8 b; };

// ---------------- dtype detection (proven) ---------------------------------
__global__ void detect_kernel(const u16* __restrict__ w1, int* __restrict__ flag) {
    int t = threadIdx.x, bad = 0;
    for (int i = t; i < 640; i += 64) {
        float ax = fabsf(bf2f(w1[i]));
        if (!(ax < 1e3f)) bad = 1;
    }
    unsigned long long m = __ballot(bad);
    if (t == 0) *flag = (m != 0ull) ? 1 : 0;
}

#define NWT 20
struct WArgs { const void* src[NWT]; int off16[NWT + 1]; int f32o[NWT]; };

__global__ __launch_bounds__(256)
void cvt_weights(WArgs a, const int* __restrict__ flag,
                 float* __restrict__ wbufA, u16* __restrict__ wbuf16) {
    int t = blockIdx.x * 256 + threadIdx.x;
    if (t >= a.off16[NWT]) return;
    int s = 0;
    while (a.off16[s + 1] <= t) ++s;
    int idx = t - a.off16[s];
    u16 raw; float v;
    if (*flag) { v = ((const float*)a.src[s])[idx]; raw = f2bf(v); }
    else       { raw = ((const u16*)a.src[s])[idx]; v = bf2f(raw); }
    wbuf16[t] = raw;
    if (a.f32o[s] >= 0) wbufA[a.f32o[s] + idx] = v;
}

// ---------------- embed: coords+3ch -> 128(gelu) -> 64, MFMA ---------------
__global__ __launch_bounds__(256, 3)
void embed_mfma(const void* __restrict__ vin, const int* __restrict__ flag,
                const float* __restrict__ W1, const float* __restrict__ b1,
                const u16* __restrict__ W2bf, const float* __restrict__ b2,
                const int* __restrict__ pdsy, const int* __restrict__ pdsx,
                float* __restrict__ d) {
    extern __shared__ char smem[];
    u16* hsT = (u16*)smem;             // [256][64] swizzled
    u16* wl  = (u16*)(smem + 32768);   // [64][64] swizzled
    int n = blockIdx.x, t = threadIdx.x;
    int wv = t >> 6, l = t & 63, m = l & 15, qd = l >> 4;
    int px0 = wv * 64;

    int w = n >> 4, s = n & 15;
    int b = w >> 4, wy = (w >> 2) & 3, wx = w & 3;
    int ty = s >> 2, tx = s & 3;
    int y = ((wy << 2) + ty) * 16 + (t >> 4);
    int x = ((wx << 2) + tx) * 16 + (t & 15);
    int fl = *flag;
    float in0 = ((float)y + 0.5f) * ((float)pdsy[0] * (1.0f / 256.0f));
    float in1 = ((float)x + 0.5f) * ((float)pdsx[0] * (1.0f / 256.0f));
    size_t pix = (size_t)b * 3 * 65536 + (size_t)y * 256 + (size_t)x;
    float in2 = fl ? ((const float*)vin)[pix]          : bf2f(((const u16*)vin)[pix]);
    float in3 = fl ? ((const float*)vin)[pix + 65536]  : bf2f(((const u16*)vin)[pix + 65536]);
    float in4 = fl ? ((const float*)vin)[pix + 131072] : bf2f(((const u16*)vin)[pix + 131072]);

    f32x4 acc[4][4];
    #pragma unroll
    for (int nt = 0; nt < 4; ++nt) {
        float bb = b2[nt * 16 + m];
        #pragma unroll
        for (int mt = 0; mt < 4; ++mt) acc[mt][nt] = {bb, bb, bb, bb};
    }
    for (int half = 0; half < 2; ++half) {
        if (half) __syncthreads();
        for (int h2 = 0; h2 < 64; h2 += 2) {
            int hid = half * 64 + h2;
            float ha = b1[hid] + W1[hid*5]*in0 + W1[hid*5+1]*in1 + W1[hid*5+2]*in2
                     + W1[hid*5+3]*in3 + W1[hid*5+4]*in4;
            float hb2 = b1[hid+1] + W1[hid*5+5]*in0 + W1[hid*5+6]*in1 + W1[hid*5+7]*in2
                     + W1[hid*5+8]*in3 + W1[hid*5+9]*in4;
            u32 pk = (u32)f2bf(gelu_f(ha)) | ((u32)f2bf(gelu_f(hb2)) << 16);
            *(u32*)&hsT[swz(t, h2 >> 3) + (h2 & 7)] = pk;
        }
        #pragma unroll
        for (int r = 0; r < 2; ++r) {
            int u = t + r * 256; int e = u >> 3, c8 = u & 7;
            *(uint4*)&wl[swz(e, c8)] = *(const uint4*)(W2bf + e * 128 + half * 64 + c8 * 8);
        }
        __syncthreads();
        #pragma unroll
        for (int ks = 0; ks < 2; ++ks) {
            U8 af[4], bf[4];
            #pragma unroll
            for (int mt = 0; mt < 4; ++mt)
                af[mt].u = *(const uint4*)&hsT[swz(px0 + mt*16 + m, ks*4 + qd)];
            #pragma unroll
            for (int nt = 0; nt < 4; ++nt)
                bf[nt].u = *(const uint4*)&wl[swz(nt*16 + m, ks*4 + qd)];
            #pragma unroll
            for (int mt = 0; mt < 4; ++mt)
                #pragma unroll
                for (int nt = 0; nt < 4; ++nt)
                    acc[mt][nt] = __builtin_amdgcn_mfma_f32_16x16x32_bf16(
                        af[mt].b, bf[nt].b, acc[mt][nt], 0, 0, 0);
        }
    }
    __syncthreads();
    float* eps = (float*)smem + wv * 2304;
    float* dp = d + (size_t)n * TOKSZ;
    #pragma unroll
    for (int ch2 = 0; ch2 < 2; ++ch2) {
        if (ch2) CBAR();
        #pragma unroll
        for (int mt = ch2*2; mt < ch2*2+2; ++mt)
            #pragma unroll
            for (int nt = 0; nt < 4; ++nt)
                #pragma unroll
                for (int r = 0; r < 4; ++r)
                    eps[((mt&1)*16 + qd*4 + r) * 68 + nt*16 + m] = acc[mt][nt][r];
        CBAR();
        #pragma unroll
        for (int j = 0; j < 8; ++j) {
            int f = l + 64*j; int row = f >> 4, c4 = f & 15;
            float4 v = *(float4*)&eps[row * 68 + c4 * 4];
            *(float4*)&dp[(px0 + ch2*32 + row) * 64 + c4 * 4] = v;
        }
    }
}

// ---------------- fused norm + projection (2 GEMMs, per-GEMM head base) ----
__global__ __launch_bounds__(256, 3)
void proj_kernel(const float* __restrict__ d,
                 const u16* __restrict__ Wa, const float* __restrict__ ba,
                 const u16* __restrict__ Wb, const float* __restrict__ bbp,
                 int ha, int hb,
                 u16* __restrict__ oa, u16* __restrict__ obp) {
    extern __shared__ char smem[];
    u16* xs = (u16*)smem;                      // [256][64] swizzled
    u16* wl = (u16*)(smem + 32768);            // [32][64] region (aliases sarr)
    float* sarr = (float*)(smem + 32768);
    float* murs = (float*)(smem + 40960);      // 512 B
    u16* ep = (u16*)(smem + 41472);            // 4 * 32*40 u16
    int n = blockIdx.x, t = threadIdx.x;
    const float4* gin = (const float4*)(d + (size_t)n * TOKSZ);
    int cb = (4 * t) & 63, g = t >> 4;
    float4 xv[16];
    float s0=0,s1=0,s2=0,s3=0,q0=0,q1=0,q2=0,q3=0;
    #pragma unroll
    for (int r = 0; r < 16; ++r) {
        float4 v = gin[t + r * 256]; xv[r] = v;
        s0 += v.x; q0 = fmaf(v.x, v.x, q0);
        s1 += v.y; q1 = fmaf(v.y, v.y, q1);
        s2 += v.z; q2 = fmaf(v.z, v.z, q2);
        s3 += v.w; q3 = fmaf(v.w, v.w, q3);
    }
    sarr[(cb+0)*16+g]=s0; sarr[(cb+1)*16+g]=s1; sarr[(cb+2)*16+g]=s2; sarr[(cb+3)*16+g]=s3;
    float* qarr = sarr + 1024;
    qarr[(cb+0)*16+g]=q0; qarr[(cb+1)*16+g]=q1; qarr[(cb+2)*16+g]=q2; qarr[(cb+3)*16+g]=q3;
    __syncthreads();
    if (t < 64) {
        float ss = 0.f, qq = 0.f;
        #pragma unroll
        for (int gg = 0; gg < 16; ++gg) { ss += sarr[t*16+gg]; qq += qarr[t*16+gg]; }
        float mu = ss * (1.0f/256.0f);
        float var = qq * (1.0f/256.0f) - mu * mu;
        murs[t] = mu; murs[64 + t] = rsqrtf(var + 1e-5f);
    }
    __syncthreads();
    {
        float m0 = murs[cb], m1 = murs[cb+1], m2 = murs[cb+2], m3 = murs[cb+3];
        float r0 = murs[64+cb], r1 = murs[64+cb+1], r2 = murs[64+cb+2], r3 = murs[64+cb+3];
        int c4 = t & 15;
        #pragma unroll
        for (int r = 0; r < 16; ++r) {
            float4 v = xv[r];
            int px = (t >> 4) + r * 16;
            uint2 o;
            o.x = (u32)f2bf((v.x-m0)*r0) | ((u32)f2bf((v.y-m1)*r1) << 16);
            o.y = (u32)f2bf((v.z-m2)*r2) | ((u32)f2bf((v.w-m3)*r3) << 16);
            *(uint2*)&xs[swz(px, c4 >> 1) + (c4 & 1) * 4] = o;
        }
    }
    int wv = t >> 6, l = t & 63, m = l & 15, qd = l >> 4;
    int px0 = wv * 64;
    const u16* Ws[2] = {Wa, Wb};
    const float* bs[2] = {ba, bbp};
    u16* outs[2] = {oa, obp};
    int hs[2] = {ha, hb};
    for (int ti = 0; ti < 2; ++ti) {
        if (ti) __syncthreads();
        for (int u = t; u < 256; u += 256) {
            int e = u >> 3, c8 = u & 7;
            *(uint4*)&wl[swz(e, c8)] =
                *(const uint4*)(Ws[ti] + (size_t)(hs[ti] * 16 + e) * 64 + c8 * 8);
        }
        __syncthreads();
        f32x4 acc[4][2];
        #pragma unroll
        for (int nt = 0; nt < 2; ++nt) {
            float bb = bs[ti][hs[ti] * 16 + nt * 16 + m];
            #pragma unroll
            for (int mt = 0; mt < 4; ++mt) acc[mt][nt] = {bb, bb, bb, bb};
        }
        #pragma unroll
        for (int ks = 0; ks < 2; ++ks) {
            U8 af[4], bf[2];
            #pragma unroll
            for (int mt = 0; mt < 4; ++mt)
                af[mt].u = *(const uint4*)&xs[swz(px0 + mt*16 + m, ks*4 + qd)];
            #pragma unroll
            for (int nt = 0; nt < 2; ++nt)
                bf[nt].u = *(const uint4*)&wl[swz(nt*16 + m, ks*4 + qd)];
            #pragma unroll
            for (int mt = 0; mt < 4; ++mt)
                #pragma unroll
                for (int nt = 0; nt < 2; ++nt)
                    acc[mt][nt] = __builtin_amdgcn_mfma_f32_16x16x32_bf16(
                        af[mt].b, bf[nt].b, acc[mt][nt], 0, 0, 0);
        }
        u16* epw = ep + wv * 1280;             // 32*(32+8)
        u16* dst0 = outs[ti] + (size_t)n * 8192;
        #pragma unroll
        for (int ch2 = 0; ch2 < 2; ++ch2) {
            if (ch2) CBAR();
            #pragma unroll
            for (int mt = ch2*2; mt < ch2*2+2; ++mt)
                #pragma unroll
                for (int nt = 0; nt < 2; ++nt)
                    #pragma unroll
                    for (int r = 0; r < 4; ++r)
                        epw[((mt&1)*16 + qd*4 + r) * 40 + nt*16 + m] = f2bf(acc[mt][nt][r]);
            CBAR();
            #pragma unroll
            for (int u = l; u < 128; u += 64) {
                int row = u >> 2, c8 = u & 3;
                *(uint4*)(dst0 + (size_t)(px0 + ch2*32 + row) * 32 + c8*8)
                    = *(uint4*)&epw[row * 40 + c8*8];
            }
        }
    }
}

// ---------------- scores via MFMA + softmax (CW=32 slabs) ------------------
__global__ __launch_bounds__(256, 4)
void scores_mfma(const u16* __restrict__ q, const u16* __restrict__ k,
                 int shifted, int hbase, float* __restrict__ A) {
    int w = blockIdx.x, hy = blockIdx.y, t = threadIdx.x;
    int wv = t >> 6, l = t & 63, m = l & 15, qd = l >> 4;
    int n0 = w * 16 + m;
    int ni = shifted ? shift_tok(n0) : n0;
    size_t base = (size_t)ni * 8192 + hy * 16 + (qd & 1) * 8;
    const u16* qrow = q + base;
    const u16* krow = k + base;
    int pxb = wv * 64 + (qd >> 1);
    f32x4 acc = {0.f, 0.f, 0.f, 0.f};
    for (int s = 0; s < 32; ++s) {
        U8 qa, kv;
        qa.u = *(const uint4*)(qrow + (size_t)(pxb + s*2) * 32);
        kv.u = *(const uint4*)(krow + (size_t)(pxb + s*2) * 32);
        acc = __builtin_amdgcn_mfma_f32_16x16x32_bf16(qa.b, kv.b, acc, 0, 0, 0);
    }
    __shared__ float pc[4][256];
    #pragma unroll
    for (int r = 0; r < 4; ++r) pc[wv][l * 4 + r] = acc[r];
    __syncthreads();
    if (wv == 0) {
        float* arow = A + ((size_t)(w * 4 + hbase + hy) * 16) * 16;
        #pragma unroll
        for (int r = 0; r < 4; ++r) {
            float sc = (pc[0][l*4+r] + pc[1][l*4+r] + pc[2][l*4+r] + pc[3][l*4+r])
                     * (1.0f / 1024.0f);
            float mx = sc;
            #pragma unroll
            for (int off = 1; off < 16; off <<= 1) mx = fmaxf(mx, __shfl_xor(mx, off, 16));
            float e = expf(sc - mx);
            float ssum = e;
            #pragma unroll
            for (int off = 1; off < 16; off <<= 1) ssum += __shfl_xor(ssum, off, 16);
            arow[(qd * 4 + r) * 16 + m] = e / ssum;
        }
    }
}

// ---------------- fused A@v + Wo MFMA + residual RMW -----------------------
// block = one (window-view) token; o-tile computed in-block from v slabs.
// XCD swizzle: all 16 token-blocks of a window land on one XCD (%8 heuristic).
__global__ __launch_bounds__(256, 3)
void wo_av(const u16* __restrict__ v1, const u16* __restrict__ v2,
           const float* __restrict__ A,
           const u16* __restrict__ Wo, const float* __restrict__ bo,
           int shifted, float* __restrict__ dres) {
    extern __shared__ char smem[];
    u16* xs = (u16*)smem;               // [256][64] swz: o-tile bf16
    u16* wl = (u16*)(smem + 32768);     // [64][64] swz
    float* As = (float*)(smem + 40960); // [4 heads][16 j]
    int*  nis = (int*)(smem + 41216);   // 16
    int bid = blockIdx.x;
    int qg = bid >> 7, r7 = bid & 127;
    int n = ((qg << 3) + (r7 & 7)) * 16 + (r7 >> 3);
    int t = threadIdx.x;
    int wv = t >> 6, l = t & 63, m = l & 15, qd = l >> 4;
    int px0 = wv * 64;
    int w = n >> 4, i = n & 15;
    int no = shifted ? shift_tok(n) : n;
    if (t < 16) { int nn = w * 16 + t; nis[t] = shifted ? shift_tok(nn) : nn; }
    if (t >= 64 && t < 128) {
        int u = t - 64;
        As[u] = A[(size_t)(w * 4 + (u >> 4)) * 256 + i * 16 + (u & 15)];
    }
    #pragma unroll
    for (int r = 0; r < 2; ++r) {
        int u = t + r * 256;
        int e = u >> 3, c8 = u & 7;
        *(uint4*)&wl[swz(e, c8)] = *(const uint4*)(Wo + e * 64 + c8 * 8);
    }
    __syncthreads();
    // o-tile = A @ v, written into xs (bf16, swizzled)
    #pragma unroll
    for (int r = 0; r < 8; ++r) {
        int idx = r * 256 + t;
        int px = idx >> 3, c8 = idx & 7, h = c8 >> 1;
        float a0=0,a1=0,a2=0,a3=0,a4=0,a5=0,a6=0,a7=0;
        #pragma unroll
        for (int j = 0; j < 16; ++j) {
            const u16* src = (c8 < 4)
                ? (v1 + (size_t)nis[j] * 8192 + px * 32 + c8 * 8)
                : (v2 + (size_t)nis[j] * 8192 + px * 32 + (c8 - 4) * 8);
            uint4 pv = *(const uint4*)src;
            float aw = As[h * 16 + j];
            a0 = fmaf(aw, __uint_as_float(pv.x << 16), a0);
            a1 = fmaf(aw, __uint_as_float(pv.x & 0xFFFF0000u), a1);
            a2 = fmaf(aw, __uint_as_float(pv.y << 16), a2);
            a3 = fmaf(aw, __uint_as_float(pv.y & 0xFFFF0000u), a3);
            a4 = fmaf(aw, __uint_as_float(pv.z << 16), a4);
            a5 = fmaf(aw, __uint_as_float(pv.z & 0xFFFF0000u), a5);
            a6 = fmaf(aw, __uint_as_float(pv.w << 16), a6);
            a7 = fmaf(aw, __uint_as_float(pv.w & 0xFFFF0000u), a7);
        }
        uint4 o;
        o.x = (u32)f2bf(a0) | ((u32)f2bf(a1) << 16);
        o.y = (u32)f2bf(a2) | ((u32)f2bf(a3) << 16);
        o.z = (u32)f2bf(a4) | ((u32)f2bf(a5) << 16);
        o.w = (u32)f2bf(a6) | ((u32)f2bf(a7) << 16);
        *(uint4*)&xs[swz(px, c8)] = o;
    }
    __syncthreads();
    // GEMM: d[no] += Wo · o + bo
    f32x4 acc[4][4];
    #pragma unroll
    for (int nt = 0; nt < 4; ++nt) {
        float bb = bo[nt * 16 + m];
        #pragma unroll
        for (int mt = 0; mt < 4; ++mt) acc[mt][nt] = {bb, bb, bb, bb};
    }
    #pragma unroll
    for (int ks = 0; ks < 2; ++ks) {
        U8 af[4], bf[4];
        #pragma unroll
        for (int mt = 0; mt < 4; ++mt)
            af[mt].u = *(const uint4*)&xs[swz(px0 + mt*16 + m, ks*4 + qd)];
        #pragma unroll
        for (int nt = 0; nt < 4; ++nt)
            bf[nt].u = *(const uint4*)&wl[swz(nt*16 + m, ks*4 + qd)];
        #pragma unroll
        for (int mt = 0; mt < 4; ++mt)
            #pragma unroll
            for (int nt = 0; nt < 4; ++nt)
                acc[mt][nt] = __builtin_amdgcn_mfma_f32_16x16x32_bf16(
                    af[mt].b, bf[nt].b, acc[mt][nt], 0, 0, 0);
    }
    __syncthreads();                     // xs/wl/As dead -> alias eps
    float* eps = (float*)smem + wv * 2304;
    float* dp = dres + (size_t)no * TOKSZ;
    #pragma unroll
    for (int ch2 = 0; ch2 < 2; ++ch2) {
        if (ch2) CBAR();
        #pragma unroll
        for (int mt = ch2*2; mt < ch2*2+2; ++mt)
            #pragma unroll
            for (int nt = 0; nt < 4; ++nt)
                #pragma unroll
                for (int r = 0; r < 4; ++r)
                    eps[((mt&1)*16 + qd*4 + r) * 68 + nt*16 + m] = acc[mt][nt][r];
        CBAR();
        #pragma unroll
        for (int j = 0; j < 8; ++j) {
            int f = l + 64*j; int row = f >> 4, c4 = f & 15;
            float4 dv = *(float4*)&eps[row * 68 + c4 * 4];
            float* gp = &dp[(px0 + ch2*32 + row) * 64 + c4 * 4];
            float4 gv = *(float4*)gp;
            gv.x += dv.x; gv.y += dv.y; gv.z += dv.z; gv.w += dv.w;
            *(float4*)gp = gv;
        }
    }
}

// ---------------- fused norm + MLP + register-residual ---------------------
__global__ __launch_bounds__(256, 3)
void mlp_fused(float* __restrict__ dres,
               const u16* __restrict__ W1, const float* __restrict__ b1,
               const u16* __restrict__ W2, const float* __restrict__ b2) {
    extern __shared__ char smem[];
    u16* xs = (u16*)smem;                      // [256][64] swizzled; xhat then h
    u16* wl = (u16*)(smem + 32768);
    float* sarr = (float*)(smem + 32768);
    float* murs = (float*)(smem + 40960);
    int n = blockIdx.x, t = threadIdx.x;
    int wv = t >> 6, l = t & 63, m = l & 15, qd = l >> 4;
    int px0 = wv * 64;
    int rbase = l >> 4, c4 = l & 15;
    const float4* gin = (const float4*)(dres + (size_t)n * TOKSZ);
    float4 xv[2][8];
    float s0=0,s1=0,s2=0,s3=0,q0=0,q1=0,q2=0,q3=0;
    #pragma unroll
    for (int ch2 = 0; ch2 < 2; ++ch2)
        #pragma unroll
        for (int j = 0; j < 8; ++j) {
            float4 v = gin[(px0 + ch2*32 + rbase + 4*j) * 16 + c4];
            xv[ch2][j] = v;
            s0 += v.x; q0 = fmaf(v.x, v.x, q0);
            s1 += v.y; q1 = fmaf(v.y, v.y, q1);
            s2 += v.z; q2 = fmaf(v.z, v.z, q2);
            s3 += v.w; q3 = fmaf(v.w, v.w, q3);
        }
    int cb = 4 * c4, g = t >> 4;
    sarr[(cb+0)*16+g]=s0; sarr[(cb+1)*16+g]=s1; sarr[(cb+2)*16+g]=s2; sarr[(cb+3)*16+g]=s3;
    float* qarr = sarr + 1024;
    qarr[(cb+0)*16+g]=q0; qarr[(cb+1)*16+g]=q1; qarr[(cb+2)*16+g]=q2; qarr[(cb+3)*16+g]=q3;
    __syncthreads();
    if (t < 64) {
        float ss = 0.f, qq = 0.f;
        #pragma unroll
        for (int gg = 0; gg < 16; ++gg) { ss += sarr[t*16+gg]; qq += qarr[t*16+gg]; }
        float mu = ss * (1.0f/256.0f);
        float var = qq * (1.0f/256.0f) - mu * mu;
        murs[t] = mu; murs[64 + t] = rsqrtf(var + 1e-5f);
    }
    __syncthreads();
    {
        float m0 = murs[cb], m1 = murs[cb+1], m2 = murs[cb+2], m3 = murs[cb+3];
        float r0 = murs[64+cb], r1 = murs[64+cb+1], r2 = murs[64+cb+2], r3 = murs[64+cb+3];
        #pragma unroll
        for (int ch2 = 0; ch2 < 2; ++ch2)
            #pragma unroll
            for (int j = 0; j < 8; ++j) {
                float4 v = xv[ch2][j];
                int row = px0 + ch2*32 + rbase + 4*j;
                uint2 o;
                o.x = (u32)f2bf((v.x-m0)*r0) | ((u32)f2bf((v.y-m1)*r1) << 16);
                o.y = (u32)f2bf((v.z-m2)*r2) | ((u32)f2bf((v.w-m3)*r3) << 16);
                *(uint2*)&xs[swz(row, c4 >> 1) + (c4 & 1) * 4] = o;
            }
    }
    #pragma unroll
    for (int r = 0; r < 2; ++r) {
        int u = t + r * 256;
        int e = u >> 3, c8 = u & 7;
        *(uint4*)&wl[swz(e, c8)] = *(const uint4*)(W1 + e * 64 + c8 * 8);
    }
    __syncthreads();
    f32x4 acc[4][4];
    #pragma unroll
    for (int nt = 0; nt < 4; ++nt) {
        float bb = b1[nt * 16 + m];
        #pragma unroll
        for (int mt = 0; mt < 4; ++mt) acc[mt][nt] = {bb, bb, bb, bb};
    }
    #pragma unroll
    for (int ks = 0; ks < 2; ++ks) {
        U8 af[4], bf[4];
        #pragma unroll
        for (int mt = 0; mt < 4; ++mt)
            af[mt].u = *(const uint4*)&xs[swz(px0 + mt*16 + m, ks*4 + qd)];
        #pragma unroll
        for (int nt = 0; nt < 4; ++nt)
            bf[nt].u = *(const uint4*)&wl[swz(nt*16 + m, ks*4 + qd)];
        #pragma unroll
        for (int mt = 0; mt < 4; ++mt)
            #pragma unroll
            for (int nt = 0; nt < 4; ++nt)
                acc[mt][nt] = __builtin_amdgcn_mfma_f32_16x16x32_bf16(
                    af[mt].b, bf[nt].b, acc[mt][nt], 0, 0, 0);
    }
    __syncthreads();
    #pragma unroll
    for (int nt = 0; nt < 4; ++nt) {
        int ch = nt * 16 + m;
        #pragma unroll
        for (int mt = 0; mt < 4; ++mt)
            #pragma unroll
            for (int r = 0; r < 4; ++r) {
                int R = px0 + mt*16 + qd*4 + r;
                xs[swz(R, ch >> 3) + (ch & 7)] = f2bf(gelu_f(acc[mt][nt][r]));
            }
    }
    #pragma unroll
    for (int r = 0; r < 2; ++r) {
        int u = t + r * 256;
        int e = u >> 3, c8 = u & 7;
        *(uint4*)&wl[swz(e, c8)] = *(const uint4*)(W2 + e * 64 + c8 * 8);
    }
    __syncthreads();
    #pragma unroll
    for (int nt = 0; nt < 4; ++nt) {
        float bb = b2[nt * 16 + m];
        #pragma unroll
        for (int mt = 0; mt < 4; ++mt) acc[mt][nt] = {bb, bb, bb, bb};
    }
    #pragma unroll
    for (int ks = 0; ks < 2; ++ks) {
        U8 af[4], bf[4];
        #pragma unroll
        for (int mt = 0; mt < 4; ++mt)
            af[mt].u = *(const uint4*)&xs[swz(px0 + mt*16 + m, ks*4 + qd)];
        #pragma unroll
        for (int nt = 0; nt < 4; ++nt)
            bf[nt].u = *(const uint4*)&wl[swz(nt*16 + m, ks*4 + qd)];
        #pragma unroll
        for (int mt = 0; mt < 4; ++mt)
            #pragma unroll
            for (int nt = 0; nt < 4; ++nt)
                acc[mt][nt] = __builtin_amdgcn_mfma_f32_16x16x32_bf16(
                    af[mt].b, bf[nt].b, acc[mt][nt], 0, 0, 0);
    }
    __syncthreads();
    float* eps = (float*)smem + wv * 2304;
    float* dp = dres + (size_t)n * TOKSZ;
    #pragma unroll
    for (int ch2 = 0; ch2 < 2; ++ch2) {
        if (ch2) CBAR();
        #pragma unroll
        for (int mt = ch2*2; mt < ch2*2+2; ++mt)
            #pragma unroll
            for (int nt = 0; nt < 4; ++nt)
                #pragma unroll
                for (int r = 0; r < 4; ++r)
                    eps[((mt&1)*16 + qd*4 + r) * 68 + nt*16 + m] = acc[mt][nt][r];
        CBAR();
        #pragma unroll
        for (int j = 0; j < 8; ++j) {
            int f = l + 64*j; int row = f >> 4, cc = f & 15;
            float4 dv = *(float4*)&eps[row * 68 + cc * 4];
            float4 bs = xv[ch2][j];                   // residual from registers
            bs.x += dv.x; bs.y += dv.y; bs.z += dv.z; bs.w += dv.w;
            *(float4*)&dp[(px0 + ch2*32 + row) * 64 + cc * 4] = bs;
        }
    }
}

// ---------------- output MLP via MFMA: 64 -> 128(gelu) -> 1 ----------------
__global__ __launch_bounds__(256, 3)
void out_mfma(const float* __restrict__ d,
              const u16* __restrict__ W1, const float* __restrict__ b1,
              const float* __restrict__ W2, const float* __restrict__ b2,
              void* __restrict__ out, const int* __restrict__ flag) {
    extern __shared__ char smem[];
    u16* xs = (u16*)smem;
    u16* wl = (u16*)(smem + 32768);
    int n = blockIdx.x, t = threadIdx.x;
    int wv = t >> 6, l = t & 63, m = l & 15, qd = l >> 4;
    int px0 = wv * 64;
    const float4* gin = (const float4*)(d + (size_t)n * TOKSZ);
    #pragma unroll
    for (int r = 0; r < 16; ++r) {
        float4 xv = gin[t + r * 256];
        int fi = t + r * 256;
        int px = fi >> 4, c4 = fi & 15;
        uint2 o;
        o.x = (u32)f2bf(xv.x) | ((u32)f2bf(xv.y) << 16);
        o.y = (u32)f2bf(xv.z) | ((u32)f2bf(xv.w) << 16);
        *(uint2*)&xs[swz(px, c4 >> 1) + (c4 & 1) * 4] = o;
    }
    float val[4][4];
    #pragma unroll
    for (int mt = 0; mt < 4; ++mt)
        #pragma unroll
        for (int r = 0; r < 4; ++r) val[mt][r] = 0.f;
    for (int nh = 0; nh < 2; ++nh) {
        if (nh) __syncthreads();
        #pragma unroll
        for (int r = 0; r < 2; ++r) {
            int u = t + r * 256;
            int e = u >> 3, c8 = u & 7;
            *(uint4*)&wl[swz(e, c8)] = *(const uint4*)(W1 + (size_t)nh * 4096 + e * 64 + c8 * 8);
        }
        __syncthreads();
        f32x4 acc[4][4];
        #pragma unroll
        for (int nt = 0; nt < 4; ++nt) {
            float bb = b1[nh * 64 + nt * 16 + m];
            #pragma unroll
            for (int mt = 0; mt < 4; ++mt) acc[mt][nt] = {bb, bb, bb, bb};
        }
        #pragma unroll
        for (int ks = 0; ks < 2; ++ks) {
            U8 af[4], bf[4];
            #pragma unroll
            for (int mt = 0; mt < 4; ++mt)
                af[mt].u = *(const uint4*)&xs[swz(px0 + mt*16 + m, ks*4 + qd)];
            #pragma unroll
            for (int nt = 0; nt < 4; ++nt)
                bf[nt].u = *(const uint4*)&wl[swz(nt*16 + m, ks*4 + qd)];
            #pragma unroll
            for (int mt = 0; mt < 4; ++mt)
                #pragma unroll
                for (int nt = 0; nt < 4; ++nt)
                    acc[mt][nt] = __builtin_amdgcn_mfma_f32_16x16x32_bf16(
                        af[mt].b, bf[nt].b, acc[mt][nt], 0, 0, 0);
        }
        float w2v[4];
        #pragma unroll
        for (int nt = 0; nt < 4; ++nt) w2v[nt] = W2[nh * 64 + nt * 16 + m];
        #pragma unroll
        for (int mt = 0; mt < 4; ++mt)
            #pragma unroll
            for (int r = 0; r < 4; ++r) {
                float p = 0.f;
                #pragma unroll
                for (int nt = 0; nt < 4; ++nt)
                    p = fmaf(gelu_f(acc[mt][nt][r]), w2v[nt], p);
                val[mt][r] += p;
            }
    }
    __syncthreads();
    float* red = (float*)smem;                 // [256][17]
    #pragma unroll
    for (int mt = 0; mt < 4; ++mt)
        #pragma unroll
        for (int r = 0; r < 4; ++r)
            red[(px0 + mt*16 + qd*4 + r) * 17 + m] = val[mt][r];
    __syncthreads();
    float a = b2[0];
    #pragma unroll
    for (int j = 0; j < 16; ++j) a += red[t * 17 + j];
    int w = n >> 4, s = n & 15;
    int b = w >> 4, wy = (w >> 2) & 3, wx = w & 3;
    int ty = s >> 2, tx = s & 3;
    int y = ((wy << 2) + ty) * 16 + (t >> 4);
    int x = ((wx << 2) + tx) * 16 + (t & 15);
    size_t oi = (size_t)b * 65536 + (size_t)y * 256 + (size_t)x;
    if (*flag) ((float*)out)[oi] = a;
    else       ((u16*)out)[oi] = f2bf(a);
}

// ---------------- host launch ----------------------------------------------
extern "C" void kernel_launch(void* const* d_in, const int* in_sizes, int n_in,
                              void* d_out, int out_size, void* d_ws, size_t ws_size,
                              hipStream_t stream) {
    (void)n_in; (void)out_size; (void)ws_size;
    const int* pdsy = (const int*)d_in[21];
    const int* pdsx = (const int*)d_in[22];

    // proven 235.65 MB layout (R8)
    char* wsb = (char*)d_ws;
    float* bufd = (float*)wsb;
    u16* qb = (u16*)(wsb + 134217728ull);
    u16* kb = (u16*)(wsb + 167772160ull);
    u16* vb = (u16*)(wsb + 201326592ull);
    float* A     = (float*)(wsb + 234881024ull);
    float* wbufA = (float*)(wsb + 235405312ull);
    u16* wbuf16  = (u16*)(wsb + 235416064ull);
    int* flag    = (int*)(wsb + 235650816ull);

    const int f32set[12] = {1, 2, 4, 6, 8, 10, 12, 14, 16, 18, 19, 20};
    WArgs wa;
    int off16[NWT + 1]; off16[0] = 0;
    int c32[NWT + 1];
    int fo = 0;
    for (int i = 0; i < NWT; ++i) {
        int di = i + 1;
        wa.src[i] = d_in[di];
        off16[i + 1] = off16[i] + in_sizes[di];
        wa.off16[i] = off16[i];
        int isf = 0;
        for (int j = 0; j < 12; ++j) if (f32set[j] == di) isf = 1;
        wa.f32o[i] = isf ? fo : -1;
        c32[di] = isf ? fo : -1;
        if (isf) fo += in_sizes[di];
    }
    wa.off16[NWT] = off16[NWT];

    detect_kernel<<<1, 64, 0, stream>>>((const u16*)d_in[1], flag);
    cvt_weights<<<(off16[NWT] + 255) / 256, 256, 0, stream>>>(wa, flag, wbufA, wbuf16);

    const float* f_inpW1 = wbufA + c32[1];
    const float* f_inpb1 = wbufA + c32[2];
    const float* f_inpb2 = wbufA + c32[4];
    const float* f_bq  = wbufA + c32[6];
    const float* f_bk  = wbufA + c32[8];
    const float* f_bv  = wbufA + c32[10];
    const float* f_bo  = wbufA + c32[12];
    const float* f_mb1 = wbufA + c32[14];
    const float* f_mb2 = wbufA + c32[16];
    const float* f_ob1 = wbufA + c32[18];
    const float* f_oW2 = wbufA + c32[19];
    const float* f_ob2 = wbufA + c32[20];
    const u16* h_inpW2 = wbuf16 + off16[2];
    const u16* h_Wq  = wbuf16 + off16[4];
    const u16* h_Wk  = wbuf16 + off16[6];
    const u16* h_Wv  = wbuf16 + off16[8];
    const u16* h_Wo  = wbuf16 + off16[10];
    const u16* h_mW1 = wbuf16 + off16[12];
    const u16* h_mW2 = wbuf16 + off16[14];
    const u16* h_oW1 = wbuf16 + off16[16];

    embed_mfma<<<NTOK, 256, 40960, stream>>>(d_in[0], flag, f_inpW1, f_inpb1,
                                             h_inpW2, f_inpb2, pdsy, pdsx, bufd);

    for (int l = 0; l < 4; ++l) {
        int sh = l & 1;
        const u16* Wql = h_Wq + l * 4096;  const float* bql = f_bq + l * 64;
        const u16* Wkl = h_Wk + l * 4096;  const float* bkl = f_bk + l * 64;
        const u16* Wvl = h_Wv + l * 4096;  const float* bvl = f_bv + l * 64;
        const u16* Wol = h_Wo + l * 4096;  const float* bol = f_bo + l * 64;
        const u16* W1l = h_mW1 + l * 4096; const float* b1l = f_mb1 + l * 64;
        const u16* W2l = h_mW2 + l * 4096; const float* b2l = f_mb2 + l * 64;

        proj_kernel<<<NTOK, 256, 51712, stream>>>(bufd, Wql, bql, Wkl, bkl, 0, 0, qb, kb);
        scores_mfma<<<dim3(128, 2), 256, 0, stream>>>(qb, kb, sh, 0, A);
        proj_kernel<<<NTOK, 256, 51712, stream>>>(bufd, Wql, bql, Wkl, bkl, 2, 2, qb, kb);
        scores_mfma<<<dim3(128, 2), 256, 0, stream>>>(qb, kb, sh, 2, A);
        proj_kernel<<<NTOK, 256, 51712, stream>>>(bufd, Wvl, bvl, Wvl, bvl, 0, 2, vb, kb);
        wo_av<<<NTOK, 256, 41280, stream>>>(vb, kb, A, Wol, bol, sh, bufd);
        mlp_fused<<<NTOK, 256, 41472, stream>>>(bufd, W1l, b1l, W2l, b2l);
    }

    out_mfma<<<NTOK, 256, 40960, stream>>>(bufd, h_oW1, f_ob1, f_oW2, f_ob2,
                                           d_out, flag);
}